// Round 5
// baseline (253.246 us; speedup 1.0000x reference)
//
#include <hip/hip_runtime.h>

// Problem: B=256, N=131072, F=16. Two-pass causal FIR with masking:
//   v[i] = (i>=16) ? x[i] + sum_{j<16} h[j]*x[i-1-j] : 0
//   y[i] = (i>=16) ? v[i] + sum_{j<16} h[15-j]*v[i-1-j] : 0
// For i >= 32, y = 33-tap conv with g = conv([1,h],[1,rev(h)]).
// i in [16,32) explicit; i < 16 zero.
//
// R6 results: 82us, WRITE=131MB (spill gone), FETCH=66MB, VALU 39%, HBM 30%,
// bank-conflict 4.7M (~4 cyc per ds_read_b128), occ 41%. Traffic is already
// optimal; kernel is serialization-bound (stage->barrier->compute) and ~18us
// of VALU is PADIDX address math.
// R6 -> R7: remove LDS entirely. Each thread: 9 coalesced global float4
// loads (one base addr + immediate offsets; lane stride 16B -> perfect
// coalescing; per-wave window ~1.2KB -> L1 serves the 8x overlap), 132 FMAs
// with g in SGPRs, 1 nt float4 store. No barrier, no LDS, no padding math.
// Boundary (1 block in 128) takes a guarded path; hot path predicate-free.

#define NROW 131072

typedef float f32x4 __attribute__((ext_vector_type(4)));

__global__ void compute_g_kernel(const float* __restrict__ h, float* __restrict__ g) {
    int m = threadIdx.x;
    if (m < 33) {
        float s = 0.f;
#pragma unroll
        for (int a = 0; a <= 16; ++a) {
            int b = m - a;
            if (b >= 0 && b <= 16) {
                float ka = (a == 0) ? 1.f : h[a - 1];
                float kb = (b == 0) ? 1.f : h[16 - b];
                s += ka * kb;
            }
        }
        g[m] = s;
    }
}

__global__ __launch_bounds__(256) void fir2_kernel(const float* __restrict__ x,
                                                   const float* __restrict__ g,
                                                   const float* __restrict__ h,
                                                   float* __restrict__ y) {
    const int bid = blockIdx.x;
    const int row = bid >> 7;          // 128 blocks per row, 1024 outputs each
    const int blk = bid & 127;
    const int t = (int)threadIdx.x;
    const int p0 = (blk << 10) + 4 * t;            // this thread's 4 outputs
    const float* __restrict__ xr = x + (size_t)row * NROW;
    float* __restrict__ yr = y + (size_t)row * NROW;

    // ---- g[0..32]: uniform indices off a uniform pointer -> s_load (SGPRs) ----
    float gg[33];
#pragma unroll
    for (int m = 0; m < 33; ++m) gg[m] = g[m];

    // ---- window w[j] = x[p0 - 32 + j], j = 0..35: 9 coalesced float4 loads ----
    float w[36];
    const float* __restrict__ wp = xr + p0 - 32;   // 16B-aligned (p0 % 4 == 0)
    if (blk != 0) {                                // hot path: no predicates
#pragma unroll
        for (int q = 0; q < 9; ++q) {
            const f32x4 v = *(const f32x4*)(wp + 4 * q);   // offset:16q folds
            w[4 * q + 0] = v.x; w[4 * q + 1] = v.y;
            w[4 * q + 2] = v.z; w[4 * q + 3] = v.w;
        }
    } else {                                       // first block of row only
#pragma unroll
        for (int q = 0; q < 9; ++q) {
            const int gidx = p0 - 32 + 4 * q;
            f32x4 v = (f32x4)(0.f);
            if (gidx >= 0) v = *(const f32x4*)(xr + gidx);
            w[4 * q + 0] = v.x; w[4 * q + 1] = v.y;
            w[4 * q + 2] = v.z; w[4 * q + 3] = v.w;
        }
    }

    f32x4 o;
#pragma unroll
    for (int c = 0; c < 4; ++c) {
        float s = 0.f;
#pragma unroll
        for (int m = 0; m < 33; ++m) s = fmaf(gg[m], w[c + 32 - m], s);
        o[c] = s;
    }
    // y never re-read: nt store keeps x L3-resident
    __builtin_nontemporal_store(o, (f32x4*)(yr + p0));

    // ---- Cold boundary fixup: outputs [0,32), first block of row, lanes 0..7 ----
    if (blk == 0 && t < 8) {
        f32x4 ofix = (f32x4)(0.f);
        if (t >= 4) {
            float hh[16];
#pragma unroll
            for (int j = 0; j < 16; ++j) hh[j] = h[j];   // uniform -> s_load
            // v[16+u] = x[16+u] + sum_j h[j] x[15+u-j]; x[0..47] are L1-hot
            float vloc[16];
#pragma unroll
            for (int u = 0; u < 16; ++u) {
                const int p = 16 + u;
                float s = xr[p];
#pragma unroll
                for (int j = 0; j < 16; ++j)
                    s = fmaf(hh[j], xr[p - 1 - j], s);
                vloc[u] = s;
            }
            // y[p] = v[p] + sum_{j<=p-17} h[15-j] v[p-1-j]; all static indexing
#pragma unroll
            for (int p = 16; p < 32; ++p) {
                float s = vloc[p - 16];
#pragma unroll
                for (int j = 0; j < 16; ++j)
                    if (j <= p - 17) s = fmaf(hh[15 - j], vloc[p - 17 - j], s);
                if ((p >> 2) == t) ofix[p & 3] = s;      // static reg index
            }
        }
        __builtin_nontemporal_store(ofix, (f32x4*)(yr + 4 * t));  // overwrite
    }
}

extern "C" void kernel_launch(void* const* d_in, const int* in_sizes, int n_in,
                              void* d_out, int out_size, void* d_ws, size_t ws_size,
                              hipStream_t stream) {
    const float* x = (const float*)d_in[0];   // (256, 131072) fp32
    const float* h = (const float*)d_in[1];   // (1, 16) fp32
    float* y = (float*)d_out;                 // (256, 131072) fp32
    float* g = (float*)d_ws;                  // 33 floats of scratch
    (void)in_sizes; (void)n_in; (void)out_size; (void)ws_size;

    compute_g_kernel<<<1, 64, 0, stream>>>(h, g);
    fir2_kernel<<<32768, 256, 0, stream>>>(x, g, h, y);
}